// Round 1
// baseline (112.109 us; speedup 1.0000x reference)
//
#include <hip/hip_runtime.h>

#define NN 4096
#define FIN 256
#define FOUT 64
#define NH 4

using f32x4 = __attribute__((ext_vector_type(4))) float;
using s16x8 = __attribute__((ext_vector_type(8))) short;

__device__ __forceinline__ unsigned short f32_to_bf16_rne(float f) {
    unsigned b = __float_as_uint(f);
    b += 0x7FFFu + ((b >> 16) & 1u);
    return (unsigned short)(b >> 16);
}

// Kernel A: Wh[h] = x @ W[h]  -> WhT bf16 [H][FOUT][NN]; s1,s2 (pre-scaled by log2 e)
__global__ __launch_bounds__(256) void k_wh(
    const float* __restrict__ x, const float* __restrict__ W,
    const float* __restrict__ a, short* __restrict__ WhT,
    float* __restrict__ s1, float* __restrict__ s2)
{
    __shared__ float xs[64][FIN];   // 64 KB
    const int nb = blockIdx.x, h = blockIdx.y, t = threadIdx.x;
    const int n0 = nb * 64;
    {
        const float4* xg = reinterpret_cast<const float4*>(x + (size_t)n0 * FIN);
        float4* xsv = reinterpret_cast<float4*>(&xs[0][0]);
        for (int k = t; k < 64 * FIN / 4; k += 256) xsv[k] = xg[k];
    }
    __syncthreads();
    const int o = t & 63, rg = t >> 6;
    float acc[16];
    #pragma unroll
    for (int r = 0; r < 16; ++r) acc[r] = 0.f;
    const float* Wp = W + (size_t)h * (FIN * FOUT) + o;
    for (int f0 = 0; f0 < FIN; f0 += 4) {
        float w0 = Wp[(f0 + 0) * FOUT];
        float w1 = Wp[(f0 + 1) * FOUT];
        float w2 = Wp[(f0 + 2) * FOUT];
        float w3 = Wp[(f0 + 3) * FOUT];
        #pragma unroll
        for (int r = 0; r < 16; ++r) {
            const float4 xv = *reinterpret_cast<const float4*>(&xs[rg * 16 + r][f0]);
            float t0 = fmaf(xv.x, w0, acc[r]);
            t0 = fmaf(xv.y, w1, t0);
            t0 = fmaf(xv.z, w2, t0);
            acc[r] = fmaf(xv.w, w3, t0);
        }
    }
    // WhT (transposed, bf16): WhT[h][o][n0 + rg*16 + r]
    alignas(16) unsigned short tmp[16];
    #pragma unroll
    for (int r = 0; r < 16; ++r) tmp[r] = f32_to_bf16_rne(acc[r]);
    short* wtp = WhT + ((size_t)h * FOUT + o) * NN + n0 + rg * 16;
    __builtin_memcpy(wtp, tmp, 32);
    // s1/s2: dot over o (64 lanes), scaled by log2(e) so main kernel uses exp2
    const float L2E = 1.4426950408889634f;
    float a1v = a[h * (2 * FOUT) + o] * L2E;
    float a2v = a[h * (2 * FOUT) + FOUT + o] * L2E;
    #pragma unroll
    for (int r = 0; r < 16; ++r) {
        float v1 = acc[r] * a1v, v2 = acc[r] * a2v;
        #pragma unroll
        for (int d = 1; d < 64; d <<= 1) {
            v1 += __shfl_xor(v1, d, 64);
            v2 += __shfl_xor(v2, d, 64);
        }
        if (o == 0) {
            s1[h * NN + n0 + rg * 16 + r] = v1;
            s2[h * NN + n0 + rg * 16 + r] = v2;
        }
    }
}

// Kernel B: per-head global max of s2 (upper bound for every row's logit max)
__global__ __launch_bounds__(256) void k_s2max(const float* __restrict__ s2,
                                               float* __restrict__ s2m)
{
    const int h = blockIdx.x, t = threadIdx.x;
    __shared__ float red[256];
    float m = -1e30f;
    for (int j = t; j < NN; j += 256) m = fmaxf(m, s2[h * NN + j]);
    red[t] = m;
    __syncthreads();
    for (int st = 128; st > 0; st >>= 1) {
        if (t < st) red[t] = fmaxf(red[t], red[t + st]);
        __syncthreads();
    }
    if (t == 0) s2m[h] = red[0];
}

// Kernel C: fused masked-softmax + PV. Block = 4 waves (one per head), 16 rows.
// grid.y = 4-way j-split; partial (acc,l) to workspace, merged by k_merge.
__global__ __launch_bounds__(256, 4) void k_attn(
    const int* __restrict__ adj, const short* __restrict__ WhT,
    const float* __restrict__ s1, const float* __restrict__ s2,
    const float* __restrict__ s2m,
    float* __restrict__ ws_acc, float* __restrict__ ws_l)
{
    __shared__ unsigned short p_lds[NH][16 * 64];   // per-wave 16x64 bf16 P tile
    const int t = threadIdx.x;
    const int lane = t & 63;
    const int h = t >> 6;          // wave = head
    const int ib = blockIdx.x;
    const int s = blockIdx.y;      // j-split
    const int i0 = ib * 16;

    float s1r[16], M[16], lsum[16];
    const float s2mv = s2m[h];
    const float* s1p = s1 + h * NN + i0;
    #pragma unroll
    for (int r = 0; r < 16; ++r) {
        float v = s1p[r];
        s1r[r] = v;
        float tt = v + s2mv;
        M[r] = fmaxf(tt, 0.2f * tt);   // LeakyReLU(s1+max s2): upper bound on row logits
        lsum[r] = 0.f;
    }
    f32x4 acc[4];
    #pragma unroll
    for (int c = 0; c < 4; ++c) acc[c] = (f32x4){0.f, 0.f, 0.f, 0.f};

    const float* s2p = s2 + h * NN;
    const int row16 = lane & 15;
    const int kbase = (lane >> 4) * 8;
    char* pw = (char*)&p_lds[h][0];
    const int wr_off = lane * 2;
    // A-frag LDS byte offsets (XOR-swizzled, const per lane)
    const int rd0 = row16 * 128 + ((kbase * 2) ^ ((row16 & 7) << 4));
    const int rd1 = row16 * 128 + (((kbase + 32) * 2) ^ ((row16 & 7) << 4));
    // B-frag base pointers: WhT[h][col][*], col = c*16 + row16
    const short* wbase = WhT + (size_t)h * FOUT * NN;
    const short* bp0 = wbase + (size_t)(0 * 16 + row16) * NN + kbase;
    const short* bp1 = wbase + (size_t)(1 * 16 + row16) * NN + kbase;
    const short* bp2 = wbase + (size_t)(2 * 16 + row16) * NN + kbase;
    const short* bp3 = wbase + (size_t)(3 * 16 + row16) * NN + kbase;

    const int adj_base = i0 * NN + lane;

    for (int jb = s * 64; jb < NN; jb += 4 * 64) {
        float s2v = s2p[jb + lane];
        #pragma unroll
        for (int r = 0; r < 16; ++r) {
            int av = adj[adj_base + r * NN + jb];
            float tt = s1r[r] + s2v;
            float e = fmaxf(tt, 0.2f * tt) - M[r];   // LR then shift; always <= 0
            float p = __builtin_amdgcn_exp2f(e);
            p = (av > 0) ? p : 0.f;
            unsigned short pb = f32_to_bf16_rne(p);
            lsum[r] += __uint_as_float((unsigned)pb << 16);  // l from rounded p (consistency)
            *(unsigned short*)(pw + (r * 128 + (wr_off ^ ((r & 7) << 4)))) = pb;
        }
        // in-wave DS ordering: writes above retire before these reads (per-wave in-order DS)
        s16x8 a0 = *(const s16x8*)(pw + rd0);
        s16x8 a1 = *(const s16x8*)(pw + rd1);
        {
            s16x8 b0 = *(const s16x8*)(bp0 + jb);
            s16x8 b1 = *(const s16x8*)(bp0 + jb + 32);
            acc[0] = __builtin_amdgcn_mfma_f32_16x16x32_bf16(a0, b0, acc[0], 0, 0, 0);
            acc[0] = __builtin_amdgcn_mfma_f32_16x16x32_bf16(a1, b1, acc[0], 0, 0, 0);
        }
        {
            s16x8 b0 = *(const s16x8*)(bp1 + jb);
            s16x8 b1 = *(const s16x8*)(bp1 + jb + 32);
            acc[1] = __builtin_amdgcn_mfma_f32_16x16x32_bf16(a0, b0, acc[1], 0, 0, 0);
            acc[1] = __builtin_amdgcn_mfma_f32_16x16x32_bf16(a1, b1, acc[1], 0, 0, 0);
        }
        {
            s16x8 b0 = *(const s16x8*)(bp2 + jb);
            s16x8 b1 = *(const s16x8*)(bp2 + jb + 32);
            acc[2] = __builtin_amdgcn_mfma_f32_16x16x32_bf16(a0, b0, acc[2], 0, 0, 0);
            acc[2] = __builtin_amdgcn_mfma_f32_16x16x32_bf16(a1, b1, acc[2], 0, 0, 0);
        }
        {
            s16x8 b0 = *(const s16x8*)(bp3 + jb);
            s16x8 b1 = *(const s16x8*)(bp3 + jb + 32);
            acc[3] = __builtin_amdgcn_mfma_f32_16x16x32_bf16(a0, b0, acc[3], 0, 0, 0);
            acc[3] = __builtin_amdgcn_mfma_f32_16x16x32_bf16(a1, b1, acc[3], 0, 0, 0);
        }
    }

    const int widx = ((ib * 4 + s) * NH + h) * 16;
    #pragma unroll
    for (int r = 0; r < 16; ++r) {
        float v = lsum[r];
        #pragma unroll
        for (int d = 1; d < 64; d <<= 1) v += __shfl_xor(v, d, 64);
        if (lane == 0) ws_l[widx + r] = v;
    }
    // store partial acc in natural [16][64] layout (D: col=lane&15, row=(lane>>4)*4+q)
    float* ap = ws_acc + (size_t)widx * 64;
    #pragma unroll
    for (int c = 0; c < 4; ++c) {
        #pragma unroll
        for (int q = 0; q < 4; ++q) {
            int row = (lane >> 4) * 4 + q;
            int col = c * 16 + row16;
            ap[row * 64 + col] = acc[c][q];
        }
    }
}

// Kernel D: merge 4 j-splits, divide by l, write out[n][h*64+o]
__global__ __launch_bounds__(256) void k_merge(
    const float* __restrict__ ws_acc, const float* __restrict__ ws_l,
    float* __restrict__ out)
{
    const int idx = blockIdx.x * 256 + threadIdx.x;
    const int o = idx & 63;
    const int h = (idx >> 6) & 3;
    const int n = idx >> 8;
    const int ib = n >> 4, r = n & 15;
    float l = 0.f, v = 0.f;
    #pragma unroll
    for (int s = 0; s < 4; ++s) {
        const int w = ((ib * 4 + s) * NH + h) * 16 + r;
        l += ws_l[w];
        v += ws_acc[(size_t)w * 64 + o];
    }
    out[idx] = v / l;
}

extern "C" void kernel_launch(void* const* d_in, const int* in_sizes, int n_in,
                              void* d_out, int out_size, void* d_ws, size_t ws_size,
                              hipStream_t stream) {
    (void)in_sizes; (void)n_in; (void)out_size; (void)ws_size;
    const float* x  = (const float*)d_in[0];
    const int*  adj = (const int*)d_in[1];
    const float* W  = (const float*)d_in[2];
    const float* a  = (const float*)d_in[3];
    float* out = (float*)d_out;
    char* ws = (char*)d_ws;
    // workspace layout (~18.4 MB)
    short* WhT   = (short*)(ws);                                        // 2 MB
    float* s1    = (float*)(ws + (2u << 20));                           // 64 KB
    float* s2    = (float*)(ws + (2u << 20) + (64u << 10));             // 64 KB
    float* s2m   = (float*)(ws + (2u << 20) + (128u << 10));            // 16 B (pad 256)
    float* ws_l  = (float*)(ws + (2u << 20) + (128u << 10) + 256);      // 256 KB
    float* ws_acc= (float*)(ws + (2u << 20) + (128u << 10) + 256 + (256u << 10)); // 16 MB

    k_wh<<<dim3(64, 4), 256, 0, stream>>>(x, W, a, WhT, s1, s2);
    k_s2max<<<4, 256, 0, stream>>>(s2, s2m);
    k_attn<<<dim3(256, 4), 256, 0, stream>>>(adj, WhT, s1, s2, s2m, ws_acc, ws_l);
    k_merge<<<4096, 256, 0, stream>>>(ws_acc, ws_l, out);
}